// Round 6
// baseline (832.830 us; speedup 1.0000x reference)
//
#include <hip/hip_runtime.h>
#include <hip/hip_bf16.h>

typedef int i32x4 __attribute__((ext_vector_type(4)));
typedef unsigned char uchar8 __attribute__((ext_vector_type(8)));
typedef unsigned char uchar4v __attribute__((ext_vector_type(4)));
typedef float float4v __attribute__((ext_vector_type(4)));

#define N_USERS 8192
#define N_ITEMS 4096
#define BATCH   2048
#define TOPK    10
#define NSUB    128          // 32 n-tiles x 4 wave-columns

__device__ __forceinline__ void gload16(const unsigned char* src, char* dst) {
    __builtin_amdgcn_global_load_lds(
        (const __attribute__((address_space(1))) unsigned int*)src,
        (__attribute__((address_space(3))) unsigned int*)dst, 16, 0, 0);
}

// ---------------------------------------------------------------------------
// Kernel 0: fp32 (exact 0/1) -> i8 + invn[row] = rsqrt(count). One block/row.
// ---------------------------------------------------------------------------
__global__ __launch_bounds__(256)
void convert_rows(const float* __restrict__ A, unsigned char* __restrict__ Ai8,
                  float* __restrict__ invn) {
    __shared__ float wsum[4];
    const int row  = blockIdx.x;
    const int tid  = threadIdx.x;
    const int wave = tid >> 6;
    const int lane = tid & 63;
    const float* src = A + (size_t)row * N_ITEMS;
    unsigned char* dst = Ai8 + (size_t)row * N_ITEMS;
    float s = 0.f;
#pragma unroll
    for (int i = 0; i < 4; ++i) {
        const int col = tid * 4 + i * 1024;
        float4v v = *(const float4v*)(src + col);
        uchar4v o;
#pragma unroll
        for (int j = 0; j < 4; ++j) {
            o[j] = (unsigned char)(v[j] != 0.f);
            s += v[j];
        }
        *(uchar4v*)(dst + col) = o;
    }
#pragma unroll
    for (int o = 32; o > 0; o >>= 1) s += __shfl_down(s, o);
    if (lane == 0) wsum[wave] = s;
    __syncthreads();
    if (tid == 0) {
        float t = wsum[0] + wsum[1] + wsum[2] + wsum[3];
        invn[row] = (t > 0.f) ? (1.0f / sqrtf(t)) : 0.f;
    }
}

// ---------------------------------------------------------------------------
// Kernel 1: 256x256 8-phase i8 GEMM (BK=128, mfma_i32_16x16x64_i8) with FUSED
// per-wave-per-row top-10 selection. Instead of writing the 64 MB sim tile,
// each wave emits its per-row top-10 of its 64 cols (tie -> lowest col idx)
// to cand[b][subset][10] (float2: val, idx). k-way-selection correctness:
// global top-10 \subset union of disjoint-subset top-10s.
// ---------------------------------------------------------------------------
#define BAR_MID() do { __builtin_amdgcn_s_barrier(); \
    asm volatile("s_waitcnt lgkmcnt(0)" ::: "memory"); \
    __builtin_amdgcn_sched_barrier(0); \
    __builtin_amdgcn_s_setprio(1); } while (0)

#define BAR_END() do { __builtin_amdgcn_s_setprio(0); \
    __builtin_amdgcn_sched_barrier(0); \
    __builtin_amdgcn_s_barrier(); } while (0)

#define BAR_END_VM4() do { __builtin_amdgcn_s_setprio(0); \
    __builtin_amdgcn_sched_barrier(0); \
    asm volatile("s_waitcnt vmcnt(4)" ::: "memory"); \
    __builtin_amdgcn_sched_barrier(0); \
    __builtin_amdgcn_s_barrier(); } while (0)

#define BAR_END_VM0() do { __builtin_amdgcn_s_setprio(0); \
    __builtin_amdgcn_sched_barrier(0); \
    asm volatile("s_waitcnt vmcnt(0)" ::: "memory"); \
    __builtin_amdgcn_sched_barrier(0); \
    __builtin_amdgcn_s_barrier(); } while (0)

#define RD_A4(dst, bo, mofs) \
  _Pragma("unroll") for (int m_ = 0; m_ < 4; ++m_) { \
    dst[m_*2+0] = *(const i32x4*)(lds + (bo) + arowb + (m_+(mofs))*2048 + cb0); \
    dst[m_*2+1] = *(const i32x4*)(lds + (bo) + arowb + (m_+(mofs))*2048 + cb1); }

#define RD_B2(dst, bo, nofs) \
  _Pragma("unroll") for (int n_ = 0; n_ < 2; ++n_) { \
    dst[n_*2+0] = *(const i32x4*)(lds + (bo) + browb + (n_+(nofs))*2048 + cb0); \
    dst[n_*2+1] = *(const i32x4*)(lds + (bo) + browb + (n_+(nofs))*2048 + cb1); }

#define MMA4x2(afr, bfr, mofs, nofs) \
  _Pragma("unroll") for (int m_ = 0; m_ < 4; ++m_) \
  _Pragma("unroll") for (int n_ = 0; n_ < 2; ++n_) { \
    acc[m_+(mofs)][n_+(nofs)] = __builtin_amdgcn_mfma_i32_16x16x64_i8( \
        afr[m_*2+0], bfr[n_*2+0], acc[m_+(mofs)][n_+(nofs)], 0, 0, 0); \
    acc[m_+(mofs)][n_+(nofs)] = __builtin_amdgcn_mfma_i32_16x16x64_i8( \
        afr[m_*2+1], bfr[n_*2+1], acc[m_+(mofs)][n_+(nofs)], 0, 0, 0); }

#define WINDOW(bo, S0, S1, S2, S3, ENDW) do { \
    RD_A4(af,  bo, 0); RD_B2(bf01, bo, 0); S0; \
    BAR_MID(); MMA4x2(af,  bf01, 0, 0); BAR_END(); \
    RD_B2(bf23, bo, 2); S1; \
    BAR_MID(); MMA4x2(af,  bf23, 0, 2); BAR_END(); \
    RD_A4(af2, bo, 4); S2; \
    BAR_MID(); MMA4x2(af2, bf01, 4, 0); BAR_END(); \
    S3; \
    BAR_MID(); MMA4x2(af2, bf23, 4, 2); ENDW; \
} while (0)

__global__ __launch_bounds__(512, 2)
void sim_gemm8(const unsigned char* __restrict__ A,
               const int* __restrict__ bidx,
               const float* __restrict__ invn,
               float2* __restrict__ cand) {
    __shared__ char lds[131072];

    const int tid  = threadIdx.x;
    const int w    = tid >> 6;
    const int lane = tid & 63;
    const int m0   = blockIdx.y * 256;
    const int n0   = blockIdx.x * 256;
    const int wr = w >> 2, wc = w & 3;

    const int fr = lane & 15, ks = lane >> 4;
    const int swz = (fr & 7) << 4;
    const int cb0 = (ks * 16) ^ swz;
    const int cb1 = (ks * 16 + 64) ^ swz;
    const int arowb = wr * 16384 + fr * 128;
    const int browb = 32768 + (wc >> 1) * 16384 + ((wc & 1) * 64 + fr) * 128;

    const int sr = lane >> 3;
    const int swzcolB = ((lane & 7) ^ sr) * 16;      // bytes
    const unsigned char* pA[4];
    const unsigned char* pB[4];
#pragma unroll
    for (int g = 0; g < 4; ++g) {
        const int row = g * 64 + w * 8 + sr;
        pA[g] = A + (size_t)bidx[m0 + row] * N_ITEMS + swzcolB;
        pB[g] = A + (size_t)(n0 + row) * N_ITEMS + swzcolB;
    }

    i32x4 acc[8][4] = {};
    i32x4 af[8], af2[8], bf01[4], bf23[4];

#define STA(U, h) do { \
    char* d_ = lds + (((U) & 1) * 65536) + (h) * 16384 + w * 1024; \
    const int k0_ = (U) * 128; \
    gload16(pA[(h)*2+0] + k0_, d_); \
    gload16(pA[(h)*2+1] + k0_, d_ + 8192); } while (0)

#define STB(U, h) do { \
    char* d_ = lds + (((U) & 1) * 65536) + 32768 + (h) * 16384 + w * 1024; \
    const int k0_ = (U) * 128; \
    gload16(pB[(h)*2+0] + k0_, d_); \
    gload16(pB[(h)*2+1] + k0_, d_ + 8192); } while (0)

    STA(0, 0); STA(0, 1); STB(0, 0); STB(0, 1); STA(1, 0); STA(1, 1);
    asm volatile("s_waitcnt vmcnt(4)" ::: "memory");
    __builtin_amdgcn_s_barrier();

    for (int i = 0; i < 15; ++i) {
        const int t1 = 2 * i + 1, t2 = 2 * i + 2, t3 = 2 * i + 3;
        WINDOW(0,     STB(t1, 0), STB(t1, 1), STA(t2, 0), STA(t2, 1), BAR_END_VM4());
        WINDOW(65536, STB(t2, 0), STB(t2, 1), STA(t3, 0), STA(t3, 1), BAR_END_VM4());
    }
    WINDOW(0,     STB(31, 0), STB(31, 1), (void)0, (void)0, BAR_END_VM0());
    WINDOW(65536, (void)0, (void)0, (void)0, (void)0, BAR_END());

    // ---- fused epilogue: normalize + self-mask + per-row top-10 of 64 cols.
    // C/D: col = lane&15 (fr), row = ks*4 + j within each 16x16 fragment.
    const int subset = blockIdx.x * 4 + wc;
#pragma unroll
    for (int mf = 0; mf < 8; ++mf) {
#pragma unroll
        for (int j = 0; j < 4; ++j) {
            const int b  = m0 + wr * 128 + mf * 16 + ks * 4 + j;
            const int ub = bidx[b];
            const float inb = invn[ub];
            float v[4]; int cidx[4];
#pragma unroll
            for (int nf = 0; nf < 4; ++nf) {
                const int nn = n0 + wc * 64 + nf * 16 + fr;
                cidx[nf] = nn;
                float x = (float)acc[mf][nf][j] * inb * invn[nn];
                if (nn == ub) x = -1e9f;
                v[nf] = x;
            }
            float rv_ = 0.f; int ri_ = 0;
#pragma unroll
            for (int it = 0; it < TOPK; ++it) {
                // local best of 4 (cidx ascending in nf -> strict > keeps lowest)
                float bv = v[0]; int bi = cidx[0];
#pragma unroll
                for (int nf = 1; nf < 4; ++nf)
                    if (v[nf] > bv) { bv = v[nf]; bi = cidx[nf]; }
                // butterfly over the 16-lane group (xor 1,2,4,8 stay in-group)
#pragma unroll
                for (int o = 1; o < 16; o <<= 1) {
                    float ov = __shfl_xor(bv, o);
                    int   oi = __shfl_xor(bi, o);
                    if (ov > bv || (ov == bv && oi < bi)) { bv = ov; bi = oi; }
                }
                if (fr == it) { rv_ = bv; ri_ = bi; }
                // knockout winner (unique col): owner lane fr == bi&15
                const int fw = bi & 15;
                const int nw = (bi - n0 - wc * 64) >> 4;
#pragma unroll
                for (int nf = 0; nf < 4; ++nf)
                    if (fr == fw && nf == nw) v[nf] = -1e30f;
            }
            if (fr < TOPK) {
                float2 e; e.x = rv_; e.y = __int_as_float(ri_);
                cand[((size_t)b * NSUB + subset) * TOPK + fr] = e;
            }
        }
    }
#undef STA
#undef STB
}

// ---------------------------------------------------------------------------
// Kernel 2: per batch row: merge 128 subsets x top-10 candidates (1280) ->
// global top-10 (tie -> lowest idx; bit-identical to full scan since subsets
// are disjoint col ranges), softmax(v/0.5), blend with i8 gathers.
// ---------------------------------------------------------------------------
__global__ __launch_bounds__(256)
void topk_blend(const float2* __restrict__ cand,
                const unsigned char* __restrict__ Ai8,
                const float* __restrict__ pred,
                float* __restrict__ out) {
    __shared__ float bvs[256];
    __shared__ int   bis[256];

    const int b    = blockIdx.x;
    const int tid  = threadIdx.x;
    const int lane = tid & 63;

    // thread owns 5 contiguous candidates of the row's 1280
    const float2* cr = cand + (size_t)b * (NSUB * TOPK);
    float cv[5]; int ci[5];
#pragma unroll
    for (int k = 0; k < 5; ++k) {
        float2 e = cr[tid * 5 + k];
        cv[k] = e.x; ci[k] = __float_as_int(e.y);
    }
    float myv = -1e30f; int myi = 0x7fffffff;
#pragma unroll
    for (int k = 0; k < 5; ++k)
        if (cv[k] > myv || (cv[k] == myv && ci[k] < myi)) { myv = cv[k]; myi = ci[k]; }
    bvs[tid] = myv; bis[tid] = myi;
    __syncthreads();

    float topv[TOPK]; int topi[TOPK];
#pragma unroll
    for (int it = 0; it < TOPK; ++it) {
        float fv = bvs[lane]; int fi = bis[lane];
#pragma unroll
        for (int g = 1; g < 4; ++g) {
            float v2 = bvs[lane + g * 64]; int i2 = bis[lane + g * 64];
            if (v2 > fv || (v2 == fv && i2 < fi)) { fv = v2; fi = i2; }
        }
#pragma unroll
        for (int o = 1; o < 64; o <<= 1) {
            float ov = __shfl_xor(fv, o);
            int   oi = __shfl_xor(fi, o);
            if (ov > fv || (ov == fv && oi < fi)) { fv = ov; fi = oi; }
        }
        topv[it] = fv; topi[it] = fi;
        __syncthreads();
        if (myi == fi) {              // unique owner (cols unique across cands)
#pragma unroll
            for (int k = 0; k < 5; ++k)
                if (ci[k] == fi) cv[k] = -1e30f;
            myv = -1e30f; myi = 0x7fffffff;
#pragma unroll
            for (int k = 0; k < 5; ++k)
                if (cv[k] > myv || (cv[k] == myv && ci[k] < myi)) { myv = cv[k]; myi = ci[k]; }
            bvs[tid] = myv; bis[tid] = myi;
        }
        __syncthreads();
    }

    // softmax over 10 (registers, redundant per thread)
    float w[TOPK];
    float mx = -1e30f;
#pragma unroll
    for (int k = 0; k < TOPK; ++k) mx = fmaxf(mx, topv[k]);
    float sumw = 0.f;
#pragma unroll
    for (int k = 0; k < TOPK; ++k) {
        w[k] = __expf((topv[k] - mx) * 2.0f);   // 1/TEMP = 2
        sumw += w[k];
    }
    const float scl = 0.3f / sumw;              // fold (1-gamma)
#pragma unroll
    for (int k = 0; k < TOPK; ++k) w[k] *= scl;

    const float* pr = pred + (size_t)b * N_ITEMS;
    float*       po = out  + (size_t)b * N_ITEMS;
#pragma unroll
    for (int h = 0; h < 2; ++h) {
        const int col = h * 2048 + tid * 8;
        float4v p0 = *(const float4v*)(pr + col);
        float4v p1 = *(const float4v*)(pr + col + 4);
        float agg[8];
#pragma unroll
        for (int j = 0; j < 8; ++j) agg[j] = 0.f;
#pragma unroll
        for (int k = 0; k < TOPK; ++k) {
            uchar8 nv = *(const uchar8*)(Ai8 + (size_t)topi[k] * N_ITEMS + col);
#pragma unroll
            for (int j = 0; j < 8; ++j) agg[j] += w[k] * (float)nv[j];
        }
        float4v o0, o1;
#pragma unroll
        for (int j = 0; j < 4; ++j) {
            o0[j] = 0.7f * p0[j] + agg[j];
            o1[j] = 0.7f * p1[j] + agg[j + 4];
        }
        *(float4v*)(po + col)     = o0;
        *(float4v*)(po + col + 4) = o1;
    }
}

extern "C" void kernel_launch(void* const* d_in, const int* in_sizes, int n_in,
                              void* d_out, int out_size, void* d_ws, size_t ws_size,
                              hipStream_t stream) {
    const float* pred = (const float*)d_in[0];
    const float* A    = (const float*)d_in[1];
    const int*   bidx = (const int*)d_in[2];
    float*       out  = (float*)d_out;

    // ws: Ai8 32 MiB | invn 32 KiB (pad 64 KiB) | cand 2048*128*10 float2 = 21 MiB
    unsigned char* Ai8  = (unsigned char*)d_ws;
    float*         invn = (float*)((char*)d_ws + (size_t)N_USERS * N_ITEMS);
    float2*        cand = (float2*)((char*)d_ws + (size_t)N_USERS * N_ITEMS + 65536);

    convert_rows<<<N_USERS, 256, 0, stream>>>(A, Ai8, invn);
    sim_gemm8<<<dim3(N_USERS / 256, BATCH / 256), 512, 0, stream>>>(Ai8, bidx, invn, cand);
    topk_blend<<<BATCH, 256, 0, stream>>>(cand, Ai8, pred, out);
}

// Round 7
// 829.511 us; speedup vs baseline: 1.0040x; 1.0040x over previous
//
#include <hip/hip_runtime.h>
#include <hip/hip_bf16.h>

typedef int i32x4 __attribute__((ext_vector_type(4)));
typedef unsigned char uchar8 __attribute__((ext_vector_type(8)));
typedef unsigned char uchar4v __attribute__((ext_vector_type(4)));
typedef float float4v __attribute__((ext_vector_type(4)));

#define N_USERS 8192
#define N_ITEMS 4096
#define BATCH   2048
#define TOPK    10
#define NSUB    128          // 32 n-tiles x 4 wave-columns

__device__ __forceinline__ void gload16(const unsigned char* src, char* dst) {
    __builtin_amdgcn_global_load_lds(
        (const __attribute__((address_space(1))) unsigned int*)src,
        (__attribute__((address_space(3))) unsigned int*)dst, 16, 0, 0);
}

// ---------------------------------------------------------------------------
// Kernel 0: fp32 (exact 0/1) -> i8 + invn[row] = rsqrt(count). One block/row.
// ---------------------------------------------------------------------------
__global__ __launch_bounds__(256)
void convert_rows(const float* __restrict__ A, unsigned char* __restrict__ Ai8,
                  float* __restrict__ invn) {
    __shared__ float wsum[4];
    const int row  = blockIdx.x;
    const int tid  = threadIdx.x;
    const int wave = tid >> 6;
    const int lane = tid & 63;
    const float* src = A + (size_t)row * N_ITEMS;
    unsigned char* dst = Ai8 + (size_t)row * N_ITEMS;
    float s = 0.f;
#pragma unroll
    for (int i = 0; i < 4; ++i) {
        const int col = tid * 4 + i * 1024;
        float4v v = *(const float4v*)(src + col);
        uchar4v o;
#pragma unroll
        for (int j = 0; j < 4; ++j) {
            o[j] = (unsigned char)(v[j] != 0.f);
            s += v[j];
        }
        *(uchar4v*)(dst + col) = o;
    }
#pragma unroll
    for (int o = 32; o > 0; o >>= 1) s += __shfl_down(s, o);
    if (lane == 0) wsum[wave] = s;
    __syncthreads();
    if (tid == 0) {
        float t = wsum[0] + wsum[1] + wsum[2] + wsum[3];
        invn[row] = (t > 0.f) ? (1.0f / sqrtf(t)) : 0.f;
    }
}

// ---------------------------------------------------------------------------
// Kernel 1: 256x256 8-phase i8 GEMM (BK=128, mfma_i32_16x16x64_i8) with FUSED
// per-wave-per-row top-10 selection (cand[b][subset][10], val+idx).
// __launch_bounds__(512, 1): grid == 256 blocks == 1/CU regardless, and the
// 256-VGPR budget keeps acc[8][4] in registers (the (512,2) 128-VGPR cap
// spilled acc into the K-loop -> 3.4 GB scratch traffic in round 6).
// ---------------------------------------------------------------------------
#define BAR_MID() do { __builtin_amdgcn_s_barrier(); \
    asm volatile("s_waitcnt lgkmcnt(0)" ::: "memory"); \
    __builtin_amdgcn_sched_barrier(0); \
    __builtin_amdgcn_s_setprio(1); } while (0)

#define BAR_END() do { __builtin_amdgcn_s_setprio(0); \
    __builtin_amdgcn_sched_barrier(0); \
    __builtin_amdgcn_s_barrier(); } while (0)

#define BAR_END_VM4() do { __builtin_amdgcn_s_setprio(0); \
    __builtin_amdgcn_sched_barrier(0); \
    asm volatile("s_waitcnt vmcnt(4)" ::: "memory"); \
    __builtin_amdgcn_sched_barrier(0); \
    __builtin_amdgcn_s_barrier(); } while (0)

#define BAR_END_VM0() do { __builtin_amdgcn_s_setprio(0); \
    __builtin_amdgcn_sched_barrier(0); \
    asm volatile("s_waitcnt vmcnt(0)" ::: "memory"); \
    __builtin_amdgcn_sched_barrier(0); \
    __builtin_amdgcn_s_barrier(); } while (0)

#define RD_A4(dst, bo, mofs) \
  _Pragma("unroll") for (int m_ = 0; m_ < 4; ++m_) { \
    dst[m_*2+0] = *(const i32x4*)(lds + (bo) + arowb + (m_+(mofs))*2048 + cb0); \
    dst[m_*2+1] = *(const i32x4*)(lds + (bo) + arowb + (m_+(mofs))*2048 + cb1); }

#define RD_B2(dst, bo, nofs) \
  _Pragma("unroll") for (int n_ = 0; n_ < 2; ++n_) { \
    dst[n_*2+0] = *(const i32x4*)(lds + (bo) + browb + (n_+(nofs))*2048 + cb0); \
    dst[n_*2+1] = *(const i32x4*)(lds + (bo) + browb + (n_+(nofs))*2048 + cb1); }

#define MMA4x2(afr, bfr, mofs, nofs) \
  _Pragma("unroll") for (int m_ = 0; m_ < 4; ++m_) \
  _Pragma("unroll") for (int n_ = 0; n_ < 2; ++n_) { \
    acc[m_+(mofs)][n_+(nofs)] = __builtin_amdgcn_mfma_i32_16x16x64_i8( \
        afr[m_*2+0], bfr[n_*2+0], acc[m_+(mofs)][n_+(nofs)], 0, 0, 0); \
    acc[m_+(mofs)][n_+(nofs)] = __builtin_amdgcn_mfma_i32_16x16x64_i8( \
        afr[m_*2+1], bfr[n_*2+1], acc[m_+(mofs)][n_+(nofs)], 0, 0, 0); }

#define WINDOW(bo, S0, S1, S2, S3, ENDW) do { \
    RD_A4(af,  bo, 0); RD_B2(bf01, bo, 0); S0; \
    BAR_MID(); MMA4x2(af,  bf01, 0, 0); BAR_END(); \
    RD_B2(bf23, bo, 2); S1; \
    BAR_MID(); MMA4x2(af,  bf23, 0, 2); BAR_END(); \
    RD_A4(af2, bo, 4); S2; \
    BAR_MID(); MMA4x2(af2, bf01, 4, 0); BAR_END(); \
    S3; \
    BAR_MID(); MMA4x2(af2, bf23, 4, 2); ENDW; \
} while (0)

__global__ __launch_bounds__(512, 1)
void sim_gemm8(const unsigned char* __restrict__ A,
               const int* __restrict__ bidx,
               const float* __restrict__ invn,
               float2* __restrict__ cand) {
    __shared__ char lds[131072];

    const int tid  = threadIdx.x;
    const int w    = tid >> 6;
    const int lane = tid & 63;
    const int m0   = blockIdx.y * 256;
    const int n0   = blockIdx.x * 256;
    const int wr = w >> 2, wc = w & 3;

    const int fr = lane & 15, ks = lane >> 4;
    const int swz = (fr & 7) << 4;
    const int cb0 = (ks * 16) ^ swz;
    const int cb1 = (ks * 16 + 64) ^ swz;
    const int arowb = wr * 16384 + fr * 128;
    const int browb = 32768 + (wc >> 1) * 16384 + ((wc & 1) * 64 + fr) * 128;

    const int sr = lane >> 3;
    const int swzcolB = ((lane & 7) ^ sr) * 16;      // bytes
    const unsigned char* pA[4];
    const unsigned char* pB[4];
#pragma unroll
    for (int g = 0; g < 4; ++g) {
        const int row = g * 64 + w * 8 + sr;
        pA[g] = A + (size_t)bidx[m0 + row] * N_ITEMS + swzcolB;
        pB[g] = A + (size_t)(n0 + row) * N_ITEMS + swzcolB;
    }

    i32x4 acc[8][4] = {};
    i32x4 af[8], af2[8], bf01[4], bf23[4];

#define STA(U, h) do { \
    char* d_ = lds + (((U) & 1) * 65536) + (h) * 16384 + w * 1024; \
    const int k0_ = (U) * 128; \
    gload16(pA[(h)*2+0] + k0_, d_); \
    gload16(pA[(h)*2+1] + k0_, d_ + 8192); } while (0)

#define STB(U, h) do { \
    char* d_ = lds + (((U) & 1) * 65536) + 32768 + (h) * 16384 + w * 1024; \
    const int k0_ = (U) * 128; \
    gload16(pB[(h)*2+0] + k0_, d_); \
    gload16(pB[(h)*2+1] + k0_, d_ + 8192); } while (0)

    STA(0, 0); STA(0, 1); STB(0, 0); STB(0, 1); STA(1, 0); STA(1, 1);
    asm volatile("s_waitcnt vmcnt(4)" ::: "memory");
    __builtin_amdgcn_s_barrier();

    for (int i = 0; i < 15; ++i) {
        const int t1 = 2 * i + 1, t2 = 2 * i + 2, t3 = 2 * i + 3;
        WINDOW(0,     STB(t1, 0), STB(t1, 1), STA(t2, 0), STA(t2, 1), BAR_END_VM4());
        WINDOW(65536, STB(t2, 0), STB(t2, 1), STA(t3, 0), STA(t3, 1), BAR_END_VM4());
    }
    WINDOW(0,     STB(31, 0), STB(31, 1), (void)0, (void)0, BAR_END_VM0());
    WINDOW(65536, (void)0, (void)0, (void)0, (void)0, BAR_END());

    // ---- fused epilogue: normalize + self-mask + per-row top-10 of 64 cols.
    // C/D: col = lane&15 (fr), row = ks*4 + j within each 16x16 fragment.
    const int subset = blockIdx.x * 4 + wc;
#pragma unroll
    for (int mf = 0; mf < 8; ++mf) {
#pragma unroll
        for (int j = 0; j < 4; ++j) {
            const int b  = m0 + wr * 128 + mf * 16 + ks * 4 + j;
            const int ub = bidx[b];
            const float inb = invn[ub];
            float v[4]; int cidx[4];
#pragma unroll
            for (int nf = 0; nf < 4; ++nf) {
                const int nn = n0 + wc * 64 + nf * 16 + fr;
                cidx[nf] = nn;
                float x = (float)acc[mf][nf][j] * inb * invn[nn];
                if (nn == ub) x = -1e9f;
                v[nf] = x;
            }
            float rv_ = 0.f; int ri_ = 0;
#pragma unroll
            for (int it = 0; it < TOPK; ++it) {
                // local best of 4 (cidx ascending in nf -> strict > keeps lowest)
                float bv = v[0]; int bi = cidx[0];
#pragma unroll
                for (int nf = 1; nf < 4; ++nf)
                    if (v[nf] > bv) { bv = v[nf]; bi = cidx[nf]; }
                // butterfly over the 16-lane group (xor 1,2,4,8 stay in-group)
#pragma unroll
                for (int o = 1; o < 16; o <<= 1) {
                    float ov = __shfl_xor(bv, o);
                    int   oi = __shfl_xor(bi, o);
                    if (ov > bv || (ov == bv && oi < bi)) { bv = ov; bi = oi; }
                }
                if (fr == it) { rv_ = bv; ri_ = bi; }
                // knockout winner (unique col): owner lane fr == bi&15
                const int fw = bi & 15;
                const int nw = (bi - n0 - wc * 64) >> 4;
#pragma unroll
                for (int nf = 0; nf < 4; ++nf)
                    if (fr == fw && nf == nw) v[nf] = -1e30f;
            }
            if (fr < TOPK) {
                float2 e; e.x = rv_; e.y = __int_as_float(ri_);
                cand[((size_t)b * NSUB + subset) * TOPK + fr] = e;
            }
        }
    }
#undef STA
#undef STB
}

// ---------------------------------------------------------------------------
// Kernel 2: per batch row: merge 128 subsets x top-10 candidates (1280) ->
// global top-10 (tie -> lowest idx; bit-identical to full scan since subsets
// are disjoint col ranges), softmax(v/0.5), blend with i8 gathers.
// ---------------------------------------------------------------------------
__global__ __launch_bounds__(256)
void topk_blend(const float2* __restrict__ cand,
                const unsigned char* __restrict__ Ai8,
                const float* __restrict__ pred,
                float* __restrict__ out) {
    __shared__ float bvs[256];
    __shared__ int   bis[256];

    const int b    = blockIdx.x;
    const int tid  = threadIdx.x;
    const int lane = tid & 63;

    // thread owns 5 contiguous candidates of the row's 1280
    const float2* cr = cand + (size_t)b * (NSUB * TOPK);
    float cv[5]; int ci[5];
#pragma unroll
    for (int k = 0; k < 5; ++k) {
        float2 e = cr[tid * 5 + k];
        cv[k] = e.x; ci[k] = __float_as_int(e.y);
    }
    float myv = -1e30f; int myi = 0x7fffffff;
#pragma unroll
    for (int k = 0; k < 5; ++k)
        if (cv[k] > myv || (cv[k] == myv && ci[k] < myi)) { myv = cv[k]; myi = ci[k]; }
    bvs[tid] = myv; bis[tid] = myi;
    __syncthreads();

    float topv[TOPK]; int topi[TOPK];
#pragma unroll
    for (int it = 0; it < TOPK; ++it) {
        float fv = bvs[lane]; int fi = bis[lane];
#pragma unroll
        for (int g = 1; g < 4; ++g) {
            float v2 = bvs[lane + g * 64]; int i2 = bis[lane + g * 64];
            if (v2 > fv || (v2 == fv && i2 < fi)) { fv = v2; fi = i2; }
        }
#pragma unroll
        for (int o = 1; o < 64; o <<= 1) {
            float ov = __shfl_xor(fv, o);
            int   oi = __shfl_xor(fi, o);
            if (ov > fv || (ov == fv && oi < fi)) { fv = ov; fi = oi; }
        }
        topv[it] = fv; topi[it] = fi;
        __syncthreads();
        if (myi == fi) {              // unique owner (cols unique across cands)
#pragma unroll
            for (int k = 0; k < 5; ++k)
                if (ci[k] == fi) cv[k] = -1e30f;
            myv = -1e30f; myi = 0x7fffffff;
#pragma unroll
            for (int k = 0; k < 5; ++k)
                if (cv[k] > myv || (cv[k] == myv && ci[k] < myi)) { myv = cv[k]; myi = ci[k]; }
            bvs[tid] = myv; bis[tid] = myi;
        }
        __syncthreads();
    }

    // softmax over 10 (registers, redundant per thread)
    float w[TOPK];
    float mx = -1e30f;
#pragma unroll
    for (int k = 0; k < TOPK; ++k) mx = fmaxf(mx, topv[k]);
    float sumw = 0.f;
#pragma unroll
    for (int k = 0; k < TOPK; ++k) {
        w[k] = __expf((topv[k] - mx) * 2.0f);   // 1/TEMP = 2
        sumw += w[k];
    }
    const float scl = 0.3f / sumw;              // fold (1-gamma)
#pragma unroll
    for (int k = 0; k < TOPK; ++k) w[k] *= scl;

    const float* pr = pred + (size_t)b * N_ITEMS;
    float*       po = out  + (size_t)b * N_ITEMS;
#pragma unroll
    for (int h = 0; h < 2; ++h) {
        const int col = h * 2048 + tid * 8;
        float4v p0 = *(const float4v*)(pr + col);
        float4v p1 = *(const float4v*)(pr + col + 4);
        float agg[8];
#pragma unroll
        for (int j = 0; j < 8; ++j) agg[j] = 0.f;
#pragma unroll
        for (int k = 0; k < TOPK; ++k) {
            uchar8 nv = *(const uchar8*)(Ai8 + (size_t)topi[k] * N_ITEMS + col);
#pragma unroll
            for (int j = 0; j < 8; ++j) agg[j] += w[k] * (float)nv[j];
        }
        float4v o0, o1;
#pragma unroll
        for (int j = 0; j < 4; ++j) {
            o0[j] = 0.7f * p0[j] + agg[j];
            o1[j] = 0.7f * p1[j] + agg[j + 4];
        }
        *(float4v*)(po + col)     = o0;
        *(float4v*)(po + col + 4) = o1;
    }
}

extern "C" void kernel_launch(void* const* d_in, const int* in_sizes, int n_in,
                              void* d_out, int out_size, void* d_ws, size_t ws_size,
                              hipStream_t stream) {
    const float* pred = (const float*)d_in[0];
    const float* A    = (const float*)d_in[1];
    const int*   bidx = (const int*)d_in[2];
    float*       out  = (float*)d_out;

    // ws: Ai8 32 MiB | invn 32 KiB (pad 64 KiB) | cand 2048*128*10 float2 = 21 MiB
    unsigned char* Ai8  = (unsigned char*)d_ws;
    float*         invn = (float*)((char*)d_ws + (size_t)N_USERS * N_ITEMS);
    float2*        cand = (float2*)((char*)d_ws + (size_t)N_USERS * N_ITEMS + 65536);

    convert_rows<<<N_USERS, 256, 0, stream>>>(A, Ai8, invn);
    sim_gemm8<<<dim3(N_USERS / 256, BATCH / 256), 512, 0, stream>>>(Ai8, bidx, invn, cand);
    topk_blend<<<BATCH, 256, 0, stream>>>(cand, Ai8, pred, out);
}

// Round 8
// 158.351 us; speedup vs baseline: 5.2594x; 5.2384x over previous
//
#include <hip/hip_runtime.h>
#include <hip/hip_bf16.h>

typedef int i32x4 __attribute__((ext_vector_type(4)));
typedef unsigned char uchar8 __attribute__((ext_vector_type(8)));
typedef unsigned char uchar4v __attribute__((ext_vector_type(4)));
typedef float float4v __attribute__((ext_vector_type(4)));

#define N_USERS 8192
#define N_ITEMS 4096
#define BATCH   2048
#define TOPK    10
#define NSUB    128          // 32 n-tiles x 4 wave-columns

__device__ __forceinline__ void gload16(const unsigned char* src, char* dst) {
    __builtin_amdgcn_global_load_lds(
        (const __attribute__((address_space(1))) unsigned int*)src,
        (__attribute__((address_space(3))) unsigned int*)dst, 16, 0, 0);
}

// ---------------------------------------------------------------------------
// Kernel 0: fp32 (exact 0/1) -> i8 + invn[row] = rsqrt(count). One block/row.
// ---------------------------------------------------------------------------
__global__ __launch_bounds__(256)
void convert_rows(const float* __restrict__ A, unsigned char* __restrict__ Ai8,
                  float* __restrict__ invn) {
    __shared__ float wsum[4];
    const int row  = blockIdx.x;
    const int tid  = threadIdx.x;
    const int wave = tid >> 6;
    const int lane = tid & 63;
    const float* src = A + (size_t)row * N_ITEMS;
    unsigned char* dst = Ai8 + (size_t)row * N_ITEMS;
    float s = 0.f;
#pragma unroll
    for (int i = 0; i < 4; ++i) {
        const int col = tid * 4 + i * 1024;
        float4v v = *(const float4v*)(src + col);
        uchar4v o;
#pragma unroll
        for (int j = 0; j < 4; ++j) {
            o[j] = (unsigned char)(v[j] != 0.f);
            s += v[j];
        }
        *(uchar4v*)(dst + col) = o;
    }
#pragma unroll
    for (int o = 32; o > 0; o >>= 1) s += __shfl_down(s, o);
    if (lane == 0) wsum[wave] = s;
    __syncthreads();
    if (tid == 0) {
        float t = wsum[0] + wsum[1] + wsum[2] + wsum[3];
        invn[row] = (t > 0.f) ? (1.0f / sqrtf(t)) : 0.f;
    }
}

// ---------------------------------------------------------------------------
// Kernel 1: 256x256 8-phase i8 GEMM (BK=128, mfma_i32_16x16x64_i8) + fused
// per-wave-per-row top-10. Register-pressure-safe epilogue: acc is converted
// and written to LDS (simple store epilogue == round-5 shape, acc stays in
// AGPRs; K-loop demand unchanged at ~250<=256), THEN a low-pressure phase
// (v[16]+~20 regs) selects top-10 from LDS. Round 6's in-register selection
// pushed live demand past the 256-VGPR cap (512-thr block => 2 waves/SIMD)
// and LLVM demoted acc to scratch inside the K-loop (3.4 GB traffic).
// ---------------------------------------------------------------------------
#define BAR_MID() do { __builtin_amdgcn_s_barrier(); \
    asm volatile("s_waitcnt lgkmcnt(0)" ::: "memory"); \
    __builtin_amdgcn_sched_barrier(0); \
    __builtin_amdgcn_s_setprio(1); } while (0)

#define BAR_END() do { __builtin_amdgcn_s_setprio(0); \
    __builtin_amdgcn_sched_barrier(0); \
    __builtin_amdgcn_s_barrier(); } while (0)

#define BAR_END_VM4() do { __builtin_amdgcn_s_setprio(0); \
    __builtin_amdgcn_sched_barrier(0); \
    asm volatile("s_waitcnt vmcnt(4)" ::: "memory"); \
    __builtin_amdgcn_sched_barrier(0); \
    __builtin_amdgcn_s_barrier(); } while (0)

#define BAR_END_VM0() do { __builtin_amdgcn_s_setprio(0); \
    __builtin_amdgcn_sched_barrier(0); \
    asm volatile("s_waitcnt vmcnt(0)" ::: "memory"); \
    __builtin_amdgcn_sched_barrier(0); \
    __builtin_amdgcn_s_barrier(); } while (0)

#define RD_A4(dst, bo, mofs) \
  _Pragma("unroll") for (int m_ = 0; m_ < 4; ++m_) { \
    dst[m_*2+0] = *(const i32x4*)(lds + (bo) + arowb + (m_+(mofs))*2048 + cb0); \
    dst[m_*2+1] = *(const i32x4*)(lds + (bo) + arowb + (m_+(mofs))*2048 + cb1); }

#define RD_B2(dst, bo, nofs) \
  _Pragma("unroll") for (int n_ = 0; n_ < 2; ++n_) { \
    dst[n_*2+0] = *(const i32x4*)(lds + (bo) + browb + (n_+(nofs))*2048 + cb0); \
    dst[n_*2+1] = *(const i32x4*)(lds + (bo) + browb + (n_+(nofs))*2048 + cb1); }

#define MMA4x2(afr, bfr, mofs, nofs) \
  _Pragma("unroll") for (int m_ = 0; m_ < 4; ++m_) \
  _Pragma("unroll") for (int n_ = 0; n_ < 2; ++n_) { \
    acc[m_+(mofs)][n_+(nofs)] = __builtin_amdgcn_mfma_i32_16x16x64_i8( \
        afr[m_*2+0], bfr[n_*2+0], acc[m_+(mofs)][n_+(nofs)], 0, 0, 0); \
    acc[m_+(mofs)][n_+(nofs)] = __builtin_amdgcn_mfma_i32_16x16x64_i8( \
        afr[m_*2+1], bfr[n_*2+1], acc[m_+(mofs)][n_+(nofs)], 0, 0, 0); }

#define WINDOW(bo, S0, S1, S2, S3, ENDW) do { \
    RD_A4(af,  bo, 0); RD_B2(bf01, bo, 0); S0; \
    BAR_MID(); MMA4x2(af,  bf01, 0, 0); BAR_END(); \
    RD_B2(bf23, bo, 2); S1; \
    BAR_MID(); MMA4x2(af,  bf23, 0, 2); BAR_END(); \
    RD_A4(af2, bo, 4); S2; \
    BAR_MID(); MMA4x2(af2, bf01, 4, 0); BAR_END(); \
    S3; \
    BAR_MID(); MMA4x2(af2, bf23, 4, 2); ENDW; \
} while (0)

__global__ __launch_bounds__(512, 2)
void sim_gemm8(const unsigned char* __restrict__ A,
               const int* __restrict__ bidx,
               const float* __restrict__ invn,
               float2* __restrict__ cand) {
    // 128 KiB staging (K-loop) ; epilogue reuses [0, 133120) as 8 waves x
    // 4 slices x (16 rows x 65 floats) for the selection phase.
    __shared__ char lds[133120];

    const int tid  = threadIdx.x;
    const int w    = tid >> 6;
    const int lane = tid & 63;
    const int m0   = blockIdx.y * 256;
    const int n0   = blockIdx.x * 256;
    const int wr = w >> 2, wc = w & 3;

    const int fr = lane & 15, ks = lane >> 4;
    const int swz = (fr & 7) << 4;
    const int cb0 = (ks * 16) ^ swz;
    const int cb1 = (ks * 16 + 64) ^ swz;
    const int arowb = wr * 16384 + fr * 128;
    const int browb = 32768 + (wc >> 1) * 16384 + ((wc & 1) * 64 + fr) * 128;

    const int sr = lane >> 3;
    const int swzcolB = ((lane & 7) ^ sr) * 16;      // bytes
    const unsigned char* pA[4];
    const unsigned char* pB[4];
#pragma unroll
    for (int g = 0; g < 4; ++g) {
        const int row = g * 64 + w * 8 + sr;
        pA[g] = A + (size_t)bidx[m0 + row] * N_ITEMS + swzcolB;
        pB[g] = A + (size_t)(n0 + row) * N_ITEMS + swzcolB;
    }

    i32x4 acc[8][4] = {};
    i32x4 af[8], af2[8], bf01[4], bf23[4];

#define STA(U, h) do { \
    char* d_ = lds + (((U) & 1) * 65536) + (h) * 16384 + w * 1024; \
    const int k0_ = (U) * 128; \
    gload16(pA[(h)*2+0] + k0_, d_); \
    gload16(pA[(h)*2+1] + k0_, d_ + 8192); } while (0)

#define STB(U, h) do { \
    char* d_ = lds + (((U) & 1) * 65536) + 32768 + (h) * 16384 + w * 1024; \
    const int k0_ = (U) * 128; \
    gload16(pB[(h)*2+0] + k0_, d_); \
    gload16(pB[(h)*2+1] + k0_, d_ + 8192); } while (0)

    STA(0, 0); STA(0, 1); STB(0, 0); STB(0, 1); STA(1, 0); STA(1, 1);
    asm volatile("s_waitcnt vmcnt(4)" ::: "memory");
    __builtin_amdgcn_s_barrier();

    for (int i = 0; i < 15; ++i) {
        const int t1 = 2 * i + 1, t2 = 2 * i + 2, t3 = 2 * i + 3;
        WINDOW(0,     STB(t1, 0), STB(t1, 1), STA(t2, 0), STA(t2, 1), BAR_END_VM4());
        WINDOW(65536, STB(t2, 0), STB(t2, 1), STA(t3, 0), STA(t3, 1), BAR_END_VM4());
    }
    WINDOW(0,     STB(31, 0), STB(31, 1), (void)0, (void)0, BAR_END_VM0());
    WINDOW(65536, (void)0, (void)0, (void)0, (void)0, BAR_END());

    // ---- epilogue: convert+normalize+mask acc -> LDS slices (2 passes of 4),
    // then runtime-loop top-10 selection from LDS (wave-local, no barriers).
    // C/D layout: row = ks*4+j, col = nf*16+fr (verified). Slice row stride
    // 65 floats (+1 pad) -> selection reads are 2-way bank aliases (free).
    const int q = ks;               // col quarter owned in selection
    const int r = fr;               // slice row owned in selection
    float invc[4];
#pragma unroll
    for (int nf = 0; nf < 4; ++nf) invc[nf] = invn[n0 + wc * 64 + nf * 16 + fr];
    const int subset = blockIdx.x * 4 + wc;
    float* slb = (float*)lds + w * 4160;     // 4 slices x 1040 floats per wave

#define CONV(mf, s) do { \
    _Pragma("unroll") for (int j = 0; j < 4; ++j) { \
        const int brow_ = m0 + wr * 128 + (mf) * 16 + ks * 4 + j; \
        const int ub_ = bidx[brow_]; \
        const float inb_ = invn[ub_]; \
        _Pragma("unroll") for (int nf = 0; nf < 4; ++nf) { \
            const int nn_ = n0 + wc * 64 + nf * 16 + fr; \
            float x_ = (float)acc[mf][nf][j] * inb_ * invc[nf]; \
            if (nn_ == ub_) x_ = -1e9f; \
            slb[(s) * 1040 + (ks * 4 + j) * 65 + nf * 16 + fr] = x_; } } } while (0)

#pragma unroll
    for (int half = 0; half < 2; ++half) {
        if (half == 0) { CONV(0, 0); CONV(1, 1); CONV(2, 2); CONV(3, 3); }
        else           { CONV(4, 0); CONV(5, 1); CONV(6, 2); CONV(7, 3); }
#pragma unroll 1
        for (int s = 0; s < 4; ++s) {
            const float* rp = slb + s * 1040 + r * 65 + q * 16;
            float v[16];
#pragma unroll
            for (int i = 0; i < 16; ++i) v[i] = rp[i];
            float wv[3] = {0.f, 0.f, 0.f};
            int   wi[3] = {0, 0, 0};
#pragma unroll
            for (int it = 0; it < TOPK; ++it) {
                // local argmax over 16 owned cols (ascending i -> lowest kept)
                float bv = v[0]; int bi = 0;
#pragma unroll
                for (int i = 1; i < 16; ++i) if (v[i] > bv) { bv = v[i]; bi = i; }
                int gc = q * 16 + bi;
                // butterfly across the 4 lanes sharing row r (xor 16, 32)
#pragma unroll
                for (int o = 16; o < 64; o <<= 1) {
                    float ov = __shfl_xor(bv, o);
                    int   oi = __shfl_xor(gc, o);
                    if (ov > bv || (ov == bv && oi < gc)) { bv = ov; gc = oi; }
                }
                if ((it & 3) == q) {        // this lane records iteration it
                    if (it < 4)      { wv[0] = bv; wi[0] = gc; }
                    else if (it < 8) { wv[1] = bv; wi[1] = gc; }
                    else             { wv[2] = bv; wi[2] = gc; }
                }
                if ((gc >> 4) == q) {       // owner knocks the winner out
#pragma unroll
                    for (int i = 0; i < 16; ++i) if ((gc & 15) == i) v[i] = -1e30f;
                }
            }
            const int brow = m0 + wr * 128 + half * 64 + s * 16 + r;
            float2* cp = cand + ((size_t)brow * NSUB + subset) * TOPK;
            float2 e0; e0.x = wv[0]; e0.y = __int_as_float(n0 + wc * 64 + wi[0]); cp[q] = e0;
            float2 e1; e1.x = wv[1]; e1.y = __int_as_float(n0 + wc * 64 + wi[1]); cp[q + 4] = e1;
            if (q < 2) {
                float2 e2; e2.x = wv[2]; e2.y = __int_as_float(n0 + wc * 64 + wi[2]); cp[q + 8] = e2;
            }
        }
    }
#undef CONV
#undef STA
#undef STB
}

// ---------------------------------------------------------------------------
// Kernel 2: per batch row: merge 128 subsets x top-10 candidates (1280) ->
// global top-10 (tie -> lowest idx; identical to full scan since subsets are
// disjoint col ranges), softmax(v/0.5), blend with i8 gathers.
// ---------------------------------------------------------------------------
__global__ __launch_bounds__(256)
void topk_blend(const float2* __restrict__ cand,
                const unsigned char* __restrict__ Ai8,
                const float* __restrict__ pred,
                float* __restrict__ out) {
    __shared__ float bvs[256];
    __shared__ int   bis[256];

    const int b    = blockIdx.x;
    const int tid  = threadIdx.x;
    const int lane = tid & 63;

    // thread owns 5 contiguous candidates of the row's 1280
    const float2* cr = cand + (size_t)b * (NSUB * TOPK);
    float cv[5]; int ci[5];
#pragma unroll
    for (int k = 0; k < 5; ++k) {
        float2 e = cr[tid * 5 + k];
        cv[k] = e.x; ci[k] = __float_as_int(e.y);
    }
    float myv = -1e30f; int myi = 0x7fffffff;
#pragma unroll
    for (int k = 0; k < 5; ++k)
        if (cv[k] > myv || (cv[k] == myv && ci[k] < myi)) { myv = cv[k]; myi = ci[k]; }
    bvs[tid] = myv; bis[tid] = myi;
    __syncthreads();

    float topv[TOPK]; int topi[TOPK];
#pragma unroll
    for (int it = 0; it < TOPK; ++it) {
        float fv = bvs[lane]; int fi = bis[lane];
#pragma unroll
        for (int g = 1; g < 4; ++g) {
            float v2 = bvs[lane + g * 64]; int i2 = bis[lane + g * 64];
            if (v2 > fv || (v2 == fv && i2 < fi)) { fv = v2; fi = i2; }
        }
#pragma unroll
        for (int o = 1; o < 64; o <<= 1) {
            float ov = __shfl_xor(fv, o);
            int   oi = __shfl_xor(fi, o);
            if (ov > fv || (ov == fv && oi < fi)) { fv = ov; fi = oi; }
        }
        topv[it] = fv; topi[it] = fi;
        __syncthreads();
        if (myi == fi) {              // unique owner (cols unique across cands)
#pragma unroll
            for (int k = 0; k < 5; ++k)
                if (ci[k] == fi) cv[k] = -1e30f;
            myv = -1e30f; myi = 0x7fffffff;
#pragma unroll
            for (int k = 0; k < 5; ++k)
                if (cv[k] > myv || (cv[k] == myv && ci[k] < myi)) { myv = cv[k]; myi = ci[k]; }
            bvs[tid] = myv; bis[tid] = myi;
        }
        __syncthreads();
    }

    // softmax over 10 (registers, redundant per thread)
    float w[TOPK];
    float mx = -1e30f;
#pragma unroll
    for (int k = 0; k < TOPK; ++k) mx = fmaxf(mx, topv[k]);
    float sumw = 0.f;
#pragma unroll
    for (int k = 0; k < TOPK; ++k) {
        w[k] = __expf((topv[k] - mx) * 2.0f);   // 1/TEMP = 2
        sumw += w[k];
    }
    const float scl = 0.3f / sumw;              // fold (1-gamma)
#pragma unroll
    for (int k = 0; k < TOPK; ++k) w[k] *= scl;

    const float* pr = pred + (size_t)b * N_ITEMS;
    float*       po = out  + (size_t)b * N_ITEMS;
#pragma unroll
    for (int h = 0; h < 2; ++h) {
        const int col = h * 2048 + tid * 8;
        float4v p0 = *(const float4v*)(pr + col);
        float4v p1 = *(const float4v*)(pr + col + 4);
        float agg[8];
#pragma unroll
        for (int j = 0; j < 8; ++j) agg[j] = 0.f;
#pragma unroll
        for (int k = 0; k < TOPK; ++k) {
            uchar8 nv = *(const uchar8*)(Ai8 + (size_t)topi[k] * N_ITEMS + col);
#pragma unroll
            for (int j = 0; j < 8; ++j) agg[j] += w[k] * (float)nv[j];
        }
        float4v o0, o1;
#pragma unroll
        for (int j = 0; j < 4; ++j) {
            o0[j] = 0.7f * p0[j] + agg[j];
            o1[j] = 0.7f * p1[j] + agg[j + 4];
        }
        *(float4v*)(po + col)     = o0;
        *(float4v*)(po + col + 4) = o1;
    }
}

extern "C" void kernel_launch(void* const* d_in, const int* in_sizes, int n_in,
                              void* d_out, int out_size, void* d_ws, size_t ws_size,
                              hipStream_t stream) {
    const float* pred = (const float*)d_in[0];
    const float* A    = (const float*)d_in[1];
    const int*   bidx = (const int*)d_in[2];
    float*       out  = (float*)d_out;

    // ws: Ai8 32 MiB | invn 32 KiB (pad 64 KiB) | cand 2048*128*10 float2 = 21 MiB
    unsigned char* Ai8  = (unsigned char*)d_ws;
    float*         invn = (float*)((char*)d_ws + (size_t)N_USERS * N_ITEMS);
    float2*        cand = (float2*)((char*)d_ws + (size_t)N_USERS * N_ITEMS + 65536);

    convert_rows<<<N_USERS, 256, 0, stream>>>(A, Ai8, invn);
    sim_gemm8<<<dim3(N_USERS / 256, BATCH / 256), 512, 0, stream>>>(Ai8, bidx, invn, cand);
    topk_blend<<<BATCH, 256, 0, stream>>>(cand, Ai8, pred, out);
}

// Round 9
// 140.500 us; speedup vs baseline: 5.9276x; 1.1271x over previous
//
#include <hip/hip_runtime.h>
#include <hip/hip_bf16.h>

typedef int i32x4 __attribute__((ext_vector_type(4)));
typedef unsigned char uchar8 __attribute__((ext_vector_type(8)));
typedef unsigned char uchar4v __attribute__((ext_vector_type(4)));
typedef float float4v __attribute__((ext_vector_type(4)));
typedef unsigned long long u64;

#define N_USERS 8192
#define N_ITEMS 4096
#define BATCH   2048
#define TOPK    10

__device__ __forceinline__ void gload16(const unsigned char* src, char* dst) {
    __builtin_amdgcn_global_load_lds(
        (const __attribute__((address_space(1))) unsigned int*)src,
        (__attribute__((address_space(3))) unsigned int*)dst, 16, 0, 0);
}

// ---------------------------------------------------------------------------
// Kernel 0: fp32 (exact 0/1) -> i8 + invn[row] = rsqrt(count). One block/row.
// ---------------------------------------------------------------------------
__global__ __launch_bounds__(256)
void convert_rows(const float* __restrict__ A, unsigned char* __restrict__ Ai8,
                  float* __restrict__ invn) {
    __shared__ float wsum[4];
    const int row  = blockIdx.x;
    const int tid  = threadIdx.x;
    const int wave = tid >> 6;
    const int lane = tid & 63;
    const float* src = A + (size_t)row * N_ITEMS;
    unsigned char* dst = Ai8 + (size_t)row * N_ITEMS;
    float s = 0.f;
#pragma unroll
    for (int i = 0; i < 4; ++i) {
        const int col = tid * 4 + i * 1024;
        float4v v = *(const float4v*)(src + col);
        uchar4v o;
#pragma unroll
        for (int j = 0; j < 4; ++j) {
            o[j] = (unsigned char)(v[j] != 0.f);
            s += v[j];
        }
        *(uchar4v*)(dst + col) = o;
    }
#pragma unroll
    for (int o = 32; o > 0; o >>= 1) s += __shfl_down(s, o);
    if (lane == 0) wsum[wave] = s;
    __syncthreads();
    if (tid == 0) {
        float t = wsum[0] + wsum[1] + wsum[2] + wsum[3];
        invn[row] = (t > 0.f) ? (1.0f / sqrtf(t)) : 0.f;
    }
}

// ---------------------------------------------------------------------------
// Kernel 1: 256x256 8-phase i8 GEMM (BK=128, mfma_i32_16x16x64_i8), writes
// fp32 sim (round-5 structure, proven ~60us / MfmaUtil ~48% / spill-free).
// Selection moved OUT (round 8's fused selection was latency-bound at
// 2 waves/SIMD and cost ~40us).
// ---------------------------------------------------------------------------
#define BAR_MID() do { __builtin_amdgcn_s_barrier(); \
    asm volatile("s_waitcnt lgkmcnt(0)" ::: "memory"); \
    __builtin_amdgcn_sched_barrier(0); \
    __builtin_amdgcn_s_setprio(1); } while (0)

#define BAR_END() do { __builtin_amdgcn_s_setprio(0); \
    __builtin_amdgcn_sched_barrier(0); \
    __builtin_amdgcn_s_barrier(); } while (0)

#define BAR_END_VM4() do { __builtin_amdgcn_s_setprio(0); \
    __builtin_amdgcn_sched_barrier(0); \
    asm volatile("s_waitcnt vmcnt(4)" ::: "memory"); \
    __builtin_amdgcn_sched_barrier(0); \
    __builtin_amdgcn_s_barrier(); } while (0)

#define BAR_END_VM0() do { __builtin_amdgcn_s_setprio(0); \
    __builtin_amdgcn_sched_barrier(0); \
    asm volatile("s_waitcnt vmcnt(0)" ::: "memory"); \
    __builtin_amdgcn_sched_barrier(0); \
    __builtin_amdgcn_s_barrier(); } while (0)

#define RD_A4(dst, bo, mofs) \
  _Pragma("unroll") for (int m_ = 0; m_ < 4; ++m_) { \
    dst[m_*2+0] = *(const i32x4*)(lds + (bo) + arowb + (m_+(mofs))*2048 + cb0); \
    dst[m_*2+1] = *(const i32x4*)(lds + (bo) + arowb + (m_+(mofs))*2048 + cb1); }

#define RD_B2(dst, bo, nofs) \
  _Pragma("unroll") for (int n_ = 0; n_ < 2; ++n_) { \
    dst[n_*2+0] = *(const i32x4*)(lds + (bo) + browb + (n_+(nofs))*2048 + cb0); \
    dst[n_*2+1] = *(const i32x4*)(lds + (bo) + browb + (n_+(nofs))*2048 + cb1); }

#define MMA4x2(afr, bfr, mofs, nofs) \
  _Pragma("unroll") for (int m_ = 0; m_ < 4; ++m_) \
  _Pragma("unroll") for (int n_ = 0; n_ < 2; ++n_) { \
    acc[m_+(mofs)][n_+(nofs)] = __builtin_amdgcn_mfma_i32_16x16x64_i8( \
        afr[m_*2+0], bfr[n_*2+0], acc[m_+(mofs)][n_+(nofs)], 0, 0, 0); \
    acc[m_+(mofs)][n_+(nofs)] = __builtin_amdgcn_mfma_i32_16x16x64_i8( \
        afr[m_*2+1], bfr[n_*2+1], acc[m_+(mofs)][n_+(nofs)], 0, 0, 0); }

#define WINDOW(bo, S0, S1, S2, S3, ENDW) do { \
    RD_A4(af,  bo, 0); RD_B2(bf01, bo, 0); S0; \
    BAR_MID(); MMA4x2(af,  bf01, 0, 0); BAR_END(); \
    RD_B2(bf23, bo, 2); S1; \
    BAR_MID(); MMA4x2(af,  bf23, 0, 2); BAR_END(); \
    RD_A4(af2, bo, 4); S2; \
    BAR_MID(); MMA4x2(af2, bf01, 4, 0); BAR_END(); \
    S3; \
    BAR_MID(); MMA4x2(af2, bf23, 4, 2); ENDW; \
} while (0)

__global__ __launch_bounds__(512, 2)
void sim_gemm8(const unsigned char* __restrict__ A,
               const int* __restrict__ bidx,
               const float* __restrict__ invn,
               float* __restrict__ sim) {
    __shared__ char lds[131072];

    const int tid  = threadIdx.x;
    const int w    = tid >> 6;
    const int lane = tid & 63;
    const int m0   = blockIdx.y * 256;
    const int n0   = blockIdx.x * 256;
    const int wr = w >> 2, wc = w & 3;

    const int fr = lane & 15, ks = lane >> 4;
    const int swz = (fr & 7) << 4;
    const int cb0 = (ks * 16) ^ swz;
    const int cb1 = (ks * 16 + 64) ^ swz;
    const int arowb = wr * 16384 + fr * 128;
    const int browb = 32768 + (wc >> 1) * 16384 + ((wc & 1) * 64 + fr) * 128;

    const int sr = lane >> 3;
    const int swzcolB = ((lane & 7) ^ sr) * 16;      // bytes
    const unsigned char* pA[4];
    const unsigned char* pB[4];
#pragma unroll
    for (int g = 0; g < 4; ++g) {
        const int row = g * 64 + w * 8 + sr;
        pA[g] = A + (size_t)bidx[m0 + row] * N_ITEMS + swzcolB;
        pB[g] = A + (size_t)(n0 + row) * N_ITEMS + swzcolB;
    }

    i32x4 acc[8][4] = {};
    i32x4 af[8], af2[8], bf01[4], bf23[4];

#define STA(U, h) do { \
    char* d_ = lds + (((U) & 1) * 65536) + (h) * 16384 + w * 1024; \
    const int k0_ = (U) * 128; \
    gload16(pA[(h)*2+0] + k0_, d_); \
    gload16(pA[(h)*2+1] + k0_, d_ + 8192); } while (0)

#define STB(U, h) do { \
    char* d_ = lds + (((U) & 1) * 65536) + 32768 + (h) * 16384 + w * 1024; \
    const int k0_ = (U) * 128; \
    gload16(pB[(h)*2+0] + k0_, d_); \
    gload16(pB[(h)*2+1] + k0_, d_ + 8192); } while (0)

    STA(0, 0); STA(0, 1); STB(0, 0); STB(0, 1); STA(1, 0); STA(1, 1);
    asm volatile("s_waitcnt vmcnt(4)" ::: "memory");
    __builtin_amdgcn_s_barrier();

    for (int i = 0; i < 15; ++i) {
        const int t1 = 2 * i + 1, t2 = 2 * i + 2, t3 = 2 * i + 3;
        WINDOW(0,     STB(t1, 0), STB(t1, 1), STA(t2, 0), STA(t2, 1), BAR_END_VM4());
        WINDOW(65536, STB(t2, 0), STB(t2, 1), STA(t3, 0), STA(t3, 1), BAR_END_VM4());
    }
    WINDOW(0,     STB(31, 0), STB(31, 1), (void)0, (void)0, BAR_END_VM0());
    WINDOW(65536, (void)0, (void)0, (void)0, (void)0, BAR_END());

    // C epilogue: normalize + self-mask; C/D: col=lane&15, row=ks*4+j (verified)
    const int crow_base = m0 + wr * 128 + ks * 4;
    const int ccol_base = n0 + wc * 64 + fr;
#pragma unroll
    for (int mf = 0; mf < 8; ++mf) {
#pragma unroll
        for (int j = 0; j < 4; ++j) {
            const int b  = crow_base + mf * 16 + j;
            const int ub = bidx[b];
            const float inb = invn[ub];
            float* rp = sim + (size_t)b * N_USERS;
#pragma unroll
            for (int nf = 0; nf < 4; ++nf) {
                const int nn = ccol_base + nf * 16;
                float v = (float)acc[mf][nf][j] * inb * invn[nn];
                if (nn == ub) v = -1e9f;
                rp[nn] = v;
            }
        }
    }
#undef STA
#undef STB
}

// ---------------------------------------------------------------------------
// Kernel 2: select10 — one wave per row, top-10 of 8192 via u64 keys.
// key = (monotone(f32) << 32) | ~idx  => u64 max == (max val, tie lowest idx),
// exactly lax.top_k semantics. Per lane: 32 float4 chunks -> 32 chunk-max keys
// (statically indexed). 10 rounds: 64-lane butterfly; owner re-reads its 16B
// chunk (L2/L3-hot) and rebuilds excluding keys >= winner (previous winners
// are exactly the larger keys). No LDS, no barriers, waves independent.
// ---------------------------------------------------------------------------
__device__ __forceinline__ u64 packkey(float f, int idx) {
    unsigned u = __float_as_uint(f);
    u = ((int)u < 0) ? ~u : (u | 0x80000000u);
    return ((u64)u << 32) | (unsigned)(~idx);
}

__global__ __launch_bounds__(256)
void select10(const float* __restrict__ sim, u64* __restrict__ keys) {
    const int wave = threadIdx.x >> 6;
    const int lane = threadIdx.x & 63;
    const int r    = blockIdx.x * 4 + wave;
    const float* sr = sim + (size_t)r * N_USERS;

    u64 cmax[32];
#pragma unroll
    for (int k = 0; k < 32; ++k) {
        const int slot = k * 64 + lane;
        float4v f = *(const float4v*)(sr + slot * 4);
        u64 a = packkey(f[0], slot * 4 + 0);
        u64 b = packkey(f[1], slot * 4 + 1);
        u64 c = packkey(f[2], slot * 4 + 2);
        u64 d = packkey(f[3], slot * 4 + 3);
        u64 ab = a > b ? a : b, cd = c > d ? c : d;
        cmax[k] = ab > cd ? ab : cd;
    }
    u64 lmax = cmax[0];
#pragma unroll
    for (int k = 1; k < 32; ++k) lmax = cmax[k] > lmax ? cmax[k] : lmax;

    u64 myout = 0;
#pragma unroll 1
    for (int it = 0; it < TOPK; ++it) {
        u64 wkey = lmax;
#pragma unroll
        for (int o = 1; o < 64; o <<= 1) {
            u64 ok = __shfl_xor(wkey, o);
            if (ok > wkey) wkey = ok;
        }
        if (lane == it) myout = wkey;
        const int widx = (int)(~(unsigned)wkey);      // low 32 bits = ~idx
        const int slot = widx >> 2;
        if (lane == (slot & 63)) {
            const int kc = slot >> 6;
            float4v f = *(const float4v*)(sr + slot * 4);
            u64 m = 0;
#pragma unroll
            for (int j = 0; j < 4; ++j) {
                u64 kj = packkey(f[j], slot * 4 + j);
                if (kj < wkey && kj > m) m = kj;
            }
#pragma unroll
            for (int k = 0; k < 32; ++k) if (k == kc) cmax[k] = m;
            lmax = cmax[0];
#pragma unroll
            for (int k = 1; k < 32; ++k) lmax = cmax[k] > lmax ? cmax[k] : lmax;
        }
    }
    if (lane < TOPK) keys[(size_t)r * TOPK + lane] = myout;
}

// ---------------------------------------------------------------------------
// Kernel 3: blend — decode 10 keys/row, softmax(v/0.5), blend with i8 gathers.
// ---------------------------------------------------------------------------
__global__ __launch_bounds__(256)
void blend(const u64* __restrict__ keys,
           const unsigned char* __restrict__ Ai8,
           const float* __restrict__ pred,
           float* __restrict__ out) {
    const int b   = blockIdx.x;
    const int tid = threadIdx.x;

    float w[TOPK]; int nid[TOPK];
    float mx = -1e30f;
#pragma unroll
    for (int k = 0; k < TOPK; ++k) {
        u64 kk = keys[(size_t)b * TOPK + k];
        unsigned hi = (unsigned)(kk >> 32);
        unsigned bits = (hi & 0x80000000u) ? (hi ^ 0x80000000u) : ~hi;
        w[k] = __uint_as_float(bits);
        nid[k] = (int)(~(unsigned)kk);
        mx = fmaxf(mx, w[k]);
    }
    float sumw = 0.f;
#pragma unroll
    for (int k = 0; k < TOPK; ++k) {
        w[k] = __expf((w[k] - mx) * 2.0f);   // 1/TEMP = 2
        sumw += w[k];
    }
    const float scl = 0.3f / sumw;           // fold (1-gamma)
#pragma unroll
    for (int k = 0; k < TOPK; ++k) w[k] *= scl;

    const float* pr = pred + (size_t)b * N_ITEMS;
    float*       po = out  + (size_t)b * N_ITEMS;
#pragma unroll
    for (int h = 0; h < 2; ++h) {
        const int col = h * 2048 + tid * 8;
        float4v p0 = *(const float4v*)(pr + col);
        float4v p1 = *(const float4v*)(pr + col + 4);
        float agg[8];
#pragma unroll
        for (int j = 0; j < 8; ++j) agg[j] = 0.f;
#pragma unroll
        for (int k = 0; k < TOPK; ++k) {
            uchar8 nv = *(const uchar8*)(Ai8 + (size_t)nid[k] * N_ITEMS + col);
#pragma unroll
            for (int j = 0; j < 8; ++j) agg[j] += w[k] * (float)nv[j];
        }
        float4v o0, o1;
#pragma unroll
        for (int j = 0; j < 4; ++j) {
            o0[j] = 0.7f * p0[j] + agg[j];
            o1[j] = 0.7f * p1[j] + agg[j + 4];
        }
        *(float4v*)(po + col)     = o0;
        *(float4v*)(po + col + 4) = o1;
    }
}

extern "C" void kernel_launch(void* const* d_in, const int* in_sizes, int n_in,
                              void* d_out, int out_size, void* d_ws, size_t ws_size,
                              hipStream_t stream) {
    const float* pred = (const float*)d_in[0];
    const float* A    = (const float*)d_in[1];
    const int*   bidx = (const int*)d_in[2];
    float*       out  = (float*)d_out;

    // ws: Ai8 32 MiB | invn 64 KiB | sim f32 64 MiB | keys 2048*10 u64 = 160 KiB
    unsigned char* Ai8  = (unsigned char*)d_ws;
    float*         invn = (float*)((char*)d_ws + (size_t)N_USERS * N_ITEMS);
    float*         sim  = (float*)((char*)d_ws + (size_t)N_USERS * N_ITEMS + 65536);
    u64*           keys = (u64*)((char*)d_ws + (size_t)N_USERS * N_ITEMS + 65536
                                 + (size_t)BATCH * N_USERS * sizeof(float));

    convert_rows<<<N_USERS, 256, 0, stream>>>(A, Ai8, invn);
    sim_gemm8<<<dim3(N_USERS / 256, BATCH / 256), 512, 0, stream>>>(Ai8, bidx, invn, sim);
    select10<<<BATCH / 4, 256, 0, stream>>>(sim, keys);
    blend<<<BATCH, 256, 0, stream>>>(keys, Ai8, pred, out);
}

// Round 10
// 134.117 us; speedup vs baseline: 6.2097x; 1.0476x over previous
//
#include <hip/hip_runtime.h>
#include <hip/hip_bf16.h>

typedef int i32x4 __attribute__((ext_vector_type(4)));
typedef unsigned char uchar8 __attribute__((ext_vector_type(8)));
typedef unsigned char uchar4v __attribute__((ext_vector_type(4)));
typedef float float4v __attribute__((ext_vector_type(4)));
typedef unsigned long long u64;

#define N_USERS 8192
#define N_ITEMS 4096
#define BATCH   2048
#define TOPK    10

__device__ __forceinline__ void gload16(const unsigned char* src, char* dst) {
    __builtin_amdgcn_global_load_lds(
        (const __attribute__((address_space(1))) unsigned int*)src,
        (__attribute__((address_space(3))) unsigned int*)dst, 16, 0, 0);
}

// ---------------------------------------------------------------------------
// Kernel 0: fp32 (exact 0/1) -> i8 + invn[row] = rsqrt(count). One block/row.
// (unchanged, proven)
// ---------------------------------------------------------------------------
__global__ __launch_bounds__(256)
void convert_rows(const float* __restrict__ A, unsigned char* __restrict__ Ai8,
                  float* __restrict__ invn) {
    __shared__ float wsum[4];
    const int row  = blockIdx.x;
    const int tid  = threadIdx.x;
    const int wave = tid >> 6;
    const int lane = tid & 63;
    const float* src = A + (size_t)row * N_ITEMS;
    unsigned char* dst = Ai8 + (size_t)row * N_ITEMS;
    float s = 0.f;
#pragma unroll
    for (int i = 0; i < 4; ++i) {
        const int col = tid * 4 + i * 1024;
        float4v v = *(const float4v*)(src + col);
        uchar4v o;
#pragma unroll
        for (int j = 0; j < 4; ++j) {
            o[j] = (unsigned char)(v[j] != 0.f);
            s += v[j];
        }
        *(uchar4v*)(dst + col) = o;
    }
#pragma unroll
    for (int o = 32; o > 0; o >>= 1) s += __shfl_down(s, o);
    if (lane == 0) wsum[wave] = s;
    __syncthreads();
    if (tid == 0) {
        float t = wsum[0] + wsum[1] + wsum[2] + wsum[3];
        invn[row] = (t > 0.f) ? (1.0f / sqrtf(t)) : 0.f;
    }
}

// ---------------------------------------------------------------------------
// Kernel 1: 256x256 8-phase i8 GEMM (BK=128, mfma_i32_16x16x64_i8), writes
// fp32 sim. (byte-identical to round 9, proven ~54us / MfmaUtil ~48%)
// ---------------------------------------------------------------------------
#define BAR_MID() do { __builtin_amdgcn_s_barrier(); \
    asm volatile("s_waitcnt lgkmcnt(0)" ::: "memory"); \
    __builtin_amdgcn_sched_barrier(0); \
    __builtin_amdgcn_s_setprio(1); } while (0)

#define BAR_END() do { __builtin_amdgcn_s_setprio(0); \
    __builtin_amdgcn_sched_barrier(0); \
    __builtin_amdgcn_s_barrier(); } while (0)

#define BAR_END_VM4() do { __builtin_amdgcn_s_setprio(0); \
    __builtin_amdgcn_sched_barrier(0); \
    asm volatile("s_waitcnt vmcnt(4)" ::: "memory"); \
    __builtin_amdgcn_sched_barrier(0); \
    __builtin_amdgcn_s_barrier(); } while (0)

#define BAR_END_VM0() do { __builtin_amdgcn_s_setprio(0); \
    __builtin_amdgcn_sched_barrier(0); \
    asm volatile("s_waitcnt vmcnt(0)" ::: "memory"); \
    __builtin_amdgcn_sched_barrier(0); \
    __builtin_amdgcn_s_barrier(); } while (0)

#define RD_A4(dst, bo, mofs) \
  _Pragma("unroll") for (int m_ = 0; m_ < 4; ++m_) { \
    dst[m_*2+0] = *(const i32x4*)(lds + (bo) + arowb + (m_+(mofs))*2048 + cb0); \
    dst[m_*2+1] = *(const i32x4*)(lds + (bo) + arowb + (m_+(mofs))*2048 + cb1); }

#define RD_B2(dst, bo, nofs) \
  _Pragma("unroll") for (int n_ = 0; n_ < 2; ++n_) { \
    dst[n_*2+0] = *(const i32x4*)(lds + (bo) + browb + (n_+(nofs))*2048 + cb0); \
    dst[n_*2+1] = *(const i32x4*)(lds + (bo) + browb + (n_+(nofs))*2048 + cb1); }

#define MMA4x2(afr, bfr, mofs, nofs) \
  _Pragma("unroll") for (int m_ = 0; m_ < 4; ++m_) \
  _Pragma("unroll") for (int n_ = 0; n_ < 2; ++n_) { \
    acc[m_+(mofs)][n_+(nofs)] = __builtin_amdgcn_mfma_i32_16x16x64_i8( \
        afr[m_*2+0], bfr[n_*2+0], acc[m_+(mofs)][n_+(nofs)], 0, 0, 0); \
    acc[m_+(mofs)][n_+(nofs)] = __builtin_amdgcn_mfma_i32_16x16x64_i8( \
        afr[m_*2+1], bfr[n_*2+1], acc[m_+(mofs)][n_+(nofs)], 0, 0, 0); }

#define WINDOW(bo, S0, S1, S2, S3, ENDW) do { \
    RD_A4(af,  bo, 0); RD_B2(bf01, bo, 0); S0; \
    BAR_MID(); MMA4x2(af,  bf01, 0, 0); BAR_END(); \
    RD_B2(bf23, bo, 2); S1; \
    BAR_MID(); MMA4x2(af,  bf23, 0, 2); BAR_END(); \
    RD_A4(af2, bo, 4); S2; \
    BAR_MID(); MMA4x2(af2, bf01, 4, 0); BAR_END(); \
    S3; \
    BAR_MID(); MMA4x2(af2, bf23, 4, 2); ENDW; \
} while (0)

__global__ __launch_bounds__(512, 2)
void sim_gemm8(const unsigned char* __restrict__ A,
               const int* __restrict__ bidx,
               const float* __restrict__ invn,
               float* __restrict__ sim) {
    __shared__ char lds[131072];

    const int tid  = threadIdx.x;
    const int w    = tid >> 6;
    const int lane = tid & 63;
    const int m0   = blockIdx.y * 256;
    const int n0   = blockIdx.x * 256;
    const int wr = w >> 2, wc = w & 3;

    const int fr = lane & 15, ks = lane >> 4;
    const int swz = (fr & 7) << 4;
    const int cb0 = (ks * 16) ^ swz;
    const int cb1 = (ks * 16 + 64) ^ swz;
    const int arowb = wr * 16384 + fr * 128;
    const int browb = 32768 + (wc >> 1) * 16384 + ((wc & 1) * 64 + fr) * 128;

    const int sr = lane >> 3;
    const int swzcolB = ((lane & 7) ^ sr) * 16;      // bytes
    const unsigned char* pA[4];
    const unsigned char* pB[4];
#pragma unroll
    for (int g = 0; g < 4; ++g) {
        const int row = g * 64 + w * 8 + sr;
        pA[g] = A + (size_t)bidx[m0 + row] * N_ITEMS + swzcolB;
        pB[g] = A + (size_t)(n0 + row) * N_ITEMS + swzcolB;
    }

    i32x4 acc[8][4] = {};
    i32x4 af[8], af2[8], bf01[4], bf23[4];

#define STA(U, h) do { \
    char* d_ = lds + (((U) & 1) * 65536) + (h) * 16384 + w * 1024; \
    const int k0_ = (U) * 128; \
    gload16(pA[(h)*2+0] + k0_, d_); \
    gload16(pA[(h)*2+1] + k0_, d_ + 8192); } while (0)

#define STB(U, h) do { \
    char* d_ = lds + (((U) & 1) * 65536) + 32768 + (h) * 16384 + w * 1024; \
    const int k0_ = (U) * 128; \
    gload16(pB[(h)*2+0] + k0_, d_); \
    gload16(pB[(h)*2+1] + k0_, d_ + 8192); } while (0)

    STA(0, 0); STA(0, 1); STB(0, 0); STB(0, 1); STA(1, 0); STA(1, 1);
    asm volatile("s_waitcnt vmcnt(4)" ::: "memory");
    __builtin_amdgcn_s_barrier();

    for (int i = 0; i < 15; ++i) {
        const int t1 = 2 * i + 1, t2 = 2 * i + 2, t3 = 2 * i + 3;
        WINDOW(0,     STB(t1, 0), STB(t1, 1), STA(t2, 0), STA(t2, 1), BAR_END_VM4());
        WINDOW(65536, STB(t2, 0), STB(t2, 1), STA(t3, 0), STA(t3, 1), BAR_END_VM4());
    }
    WINDOW(0,     STB(31, 0), STB(31, 1), (void)0, (void)0, BAR_END_VM0());
    WINDOW(65536, (void)0, (void)0, (void)0, (void)0, BAR_END());

    const int crow_base = m0 + wr * 128 + ks * 4;
    const int ccol_base = n0 + wc * 64 + fr;
#pragma unroll
    for (int mf = 0; mf < 8; ++mf) {
#pragma unroll
        for (int j = 0; j < 4; ++j) {
            const int b  = crow_base + mf * 16 + j;
            const int ub = bidx[b];
            const float inb = invn[ub];
            float* rp = sim + (size_t)b * N_USERS;
#pragma unroll
            for (int nf = 0; nf < 4; ++nf) {
                const int nn = ccol_base + nf * 16;
                float v = (float)acc[mf][nf][j] * inb * invn[nn];
                if (nn == ub) v = -1e9f;
                rp[nn] = v;
            }
        }
    }
#undef STA
#undef STB
}

// ---------------------------------------------------------------------------
// Kernel 2: select_blend — one block per batch row. Top-10 via u64 keys
// (key = monotone(f32)<<32 | ~idx => u64 max == max val, tie lowest idx),
// block-wide: each thread folds 8 float4 chunks -> chunk-max keys (static
// indexing), 2KB LDS + butterfly for extraction; only the owner thread
// rebuilds its 16B chunk per round. All threads then hold the 10 keys in
// registers -> decode, softmax(v/0.5), gather 10 i8 rows, blend. No keys
// buffer, no extra dispatch.
// ---------------------------------------------------------------------------
__device__ __forceinline__ u64 packkey(float f, int idx) {
    unsigned u = __float_as_uint(f);
    u = ((int)u < 0) ? ~u : (u | 0x80000000u);
    return ((u64)u << 32) | (unsigned)(~idx);
}

__global__ __launch_bounds__(256)
void select_blend(const float* __restrict__ sim,
                  const unsigned char* __restrict__ Ai8,
                  const float* __restrict__ pred,
                  float* __restrict__ out) {
    __shared__ u64 bvs[256];

    const int b    = blockIdx.x;
    const int tid  = threadIdx.x;
    const int lane = tid & 63;
    const float* srow = sim + (size_t)b * N_USERS;

    // fold: 8 chunks of float4 per thread (slot = tid + k*256, coalesced)
    u64 cmax[8];
#pragma unroll
    for (int k = 0; k < 8; ++k) {
        const int slot = tid + k * 256;
        float4v f = ((const float4v*)srow)[slot];
        u64 a = packkey(f[0], slot * 4 + 0);
        u64 bb = packkey(f[1], slot * 4 + 1);
        u64 c = packkey(f[2], slot * 4 + 2);
        u64 d = packkey(f[3], slot * 4 + 3);
        u64 ab = a > bb ? a : bb, cd = c > d ? c : d;
        cmax[k] = ab > cd ? ab : cd;
    }
    u64 lmax = cmax[0];
#pragma unroll
    for (int k = 1; k < 8; ++k) lmax = cmax[k] > lmax ? cmax[k] : lmax;
    bvs[tid] = lmax;
    __syncthreads();

    u64 topkeys[TOPK];
#pragma unroll
    for (int it = 0; it < TOPK; ++it) {
        u64 fv = bvs[lane];
#pragma unroll
        for (int g = 1; g < 4; ++g) {
            u64 v2 = bvs[lane + g * 64];
            if (v2 > fv) fv = v2;
        }
#pragma unroll
        for (int o = 1; o < 64; o <<= 1) {
            u64 ok = __shfl_xor(fv, o);
            if (ok > fv) fv = ok;
        }
        topkeys[it] = fv;
        __syncthreads();                      // all bvs reads done
        const int widx = (int)(~(unsigned)fv);
        const int slot = widx >> 2;
        if (tid == (slot & 255)) {            // owner rebuilds its chunk
            const int kc = slot >> 8;
            float4v f = *(const float4v*)(srow + slot * 4);
            u64 m = 0;
#pragma unroll
            for (int j = 0; j < 4; ++j) {
                u64 kj = packkey(f[j], slot * 4 + j);
                if (kj < fv && kj > m) m = kj;    // keys >= fv are prior winners
            }
#pragma unroll
            for (int k = 0; k < 8; ++k) if (k == kc) cmax[k] = m;
            u64 nl = cmax[0];
#pragma unroll
            for (int k = 1; k < 8; ++k) nl = cmax[k] > nl ? cmax[k] : nl;
            bvs[tid] = nl;
        }
        __syncthreads();
    }

    // decode + softmax (registers, redundant per thread)
    float w[TOPK]; int nid[TOPK];
    float mx = -1e30f;
#pragma unroll
    for (int k = 0; k < TOPK; ++k) {
        unsigned hi = (unsigned)(topkeys[k] >> 32);
        unsigned bits = (hi & 0x80000000u) ? (hi ^ 0x80000000u) : ~hi;
        w[k] = __uint_as_float(bits);
        nid[k] = (int)(~(unsigned)topkeys[k]);
        mx = fmaxf(mx, w[k]);
    }
    float sumw = 0.f;
#pragma unroll
    for (int k = 0; k < TOPK; ++k) {
        w[k] = __expf((w[k] - mx) * 2.0f);   // 1/TEMP = 2
        sumw += w[k];
    }
    const float scl = 0.3f / sumw;           // fold (1-gamma)
#pragma unroll
    for (int k = 0; k < TOPK; ++k) w[k] *= scl;

    const float* pr = pred + (size_t)b * N_ITEMS;
    float*       po = out  + (size_t)b * N_ITEMS;
#pragma unroll
    for (int h = 0; h < 2; ++h) {
        const int col = h * 2048 + tid * 8;
        float4v p0 = *(const float4v*)(pr + col);
        float4v p1 = *(const float4v*)(pr + col + 4);
        float agg[8];
#pragma unroll
        for (int j = 0; j < 8; ++j) agg[j] = 0.f;
#pragma unroll
        for (int k = 0; k < TOPK; ++k) {
            uchar8 nv = *(const uchar8*)(Ai8 + (size_t)nid[k] * N_ITEMS + col);
#pragma unroll
            for (int j = 0; j < 8; ++j) agg[j] += w[k] * (float)nv[j];
        }
        float4v o0, o1;
#pragma unroll
        for (int j = 0; j < 4; ++j) {
            o0[j] = 0.7f * p0[j] + agg[j];
            o1[j] = 0.7f * p1[j] + agg[j + 4];
        }
        *(float4v*)(po + col)     = o0;
        *(float4v*)(po + col + 4) = o1;
    }
}

extern "C" void kernel_launch(void* const* d_in, const int* in_sizes, int n_in,
                              void* d_out, int out_size, void* d_ws, size_t ws_size,
                              hipStream_t stream) {
    const float* pred = (const float*)d_in[0];
    const float* A    = (const float*)d_in[1];
    const int*   bidx = (const int*)d_in[2];
    float*       out  = (float*)d_out;

    // ws: Ai8 32 MiB | invn 64 KiB | sim f32 64 MiB
    unsigned char* Ai8  = (unsigned char*)d_ws;
    float*         invn = (float*)((char*)d_ws + (size_t)N_USERS * N_ITEMS);
    float*         sim  = (float*)((char*)d_ws + (size_t)N_USERS * N_ITEMS + 65536);

    convert_rows<<<N_USERS, 256, 0, stream>>>(A, Ai8, invn);
    sim_gemm8<<<dim3(N_USERS / 256, BATCH / 256), 512, 0, stream>>>(Ai8, bidx, invn, sim);
    select_blend<<<BATCH, 256, 0, stream>>>(sim, Ai8, pred, out);
}